// Round 1
// 129.739 us; speedup vs baseline: 1.0932x; 1.0932x over previous
//
#include <hip/hip_runtime.h>
#include <math.h>

#define DIM 128
#define HEADS 8
#define HD 16
#define NPOS 8192      // 32*32*8
#define EPS 1e-5f

// ---- f16 helpers -------------------------------------------------
typedef _Float16 half2_t __attribute__((ext_vector_type(2)));

static __device__ __forceinline__ half2_t u2h(unsigned u) {
    half2_t r; __builtin_memcpy(&r, &u, 4); return r;
}
static __device__ __forceinline__ unsigned pkh(float a, float b) {
    half2_t h; h.x = (_Float16)a; h.y = (_Float16)b;
    unsigned u; __builtin_memcpy(&u, &h, 4); return u;
}
// dot of one f16 channel-pair against q channel-pair, fp32 accumulate
static __device__ __forceinline__ float dot2(unsigned k, unsigned q, float acc) {
#if __has_builtin(__builtin_amdgcn_fdot2)
    return __builtin_amdgcn_fdot2(u2h(k), u2h(q), acc, false);
#else
    half2_t kh = u2h(k), qh = u2h(q);
    acc = fmaf((float)kh.x, (float)qh.x, acc);
    return fmaf((float)kh.y, (float)qh.y, acc);
#endif
}

// ---------------- instance-norm stats ----------------
// ws: [0,128) mu_x [128,256) rs_x [256,384) mu_s [384,512) rs_s
__global__ __launch_bounds__(256) void stats_kernel(const float* __restrict__ x,
                                                    const float* __restrict__ skip,
                                                    float* __restrict__ ws) {
    int c = blockIdx.x;
    const float* src; int n; float* mu_out; float* rs_out; int ci;
    if (c < DIM) { ci = c; src = x + c * 1024; n = 1024; mu_out = ws; rs_out = ws + DIM; }
    else { ci = c - DIM; src = skip + (size_t)ci * NPOS; n = NPOS; mu_out = ws + 2*DIM; rs_out = ws + 3*DIM; }
    int t = threadIdx.x;
    const float4* s4 = (const float4*)src;
    int n4 = n >> 2;
    float s = 0.f, s2 = 0.f;
    for (int i = t; i < n4; i += 256) {
        float4 v = s4[i];
        s += (v.x + v.y) + (v.z + v.w);
        s2 = fmaf(v.x, v.x, fmaf(v.y, v.y, fmaf(v.z, v.z, fmaf(v.w, v.w, s2))));
    }
    #pragma unroll
    for (int off = 32; off > 0; off >>= 1) {
        s  += __shfl_down(s,  off, 64);
        s2 += __shfl_down(s2, off, 64);
    }
    __shared__ float ls[4], ls2[4];
    int wv = t >> 6;
    if ((t & 63) == 0) { ls[wv] = s; ls2[wv] = s2; }
    __syncthreads();
    if (t == 0) {
        float S  = ls[0] + ls[1] + ls[2] + ls[3];
        float S2 = ls2[0] + ls2[1] + ls2[2] + ls2[3];
        float inv_n = 1.f / (float)n;
        float mu  = S * inv_n;
        float var = S2 * inv_n - mu * mu;
        mu_out[ci] = mu;
        rs_out[ci] = rsqrtf(var + EPS);
    }
}

// ---------------- q/k/v projections ----------------
// q has only 1024 distinct rows (x is upsampled 2x in h,w,z): which==0 only
// runs 16 tiles over the x-grid and stores f16-packed q[1024][128].
// k/v: 128 tiles over skip positions, f16-packed out (more precise than bf16
// here since |k|,|v| << 1).
__global__ __launch_bounds__(256) void qkv_kernel(const float* __restrict__ x,
                                                  const float* __restrict__ skip,
                                                  const float* __restrict__ Wq, const float* __restrict__ bq,
                                                  const float* __restrict__ Wk, const float* __restrict__ bk,
                                                  const float* __restrict__ Wv, const float* __restrict__ bv,
                                                  const float* __restrict__ ws,
                                                  unsigned* __restrict__ q_out,
                                                  unsigned* __restrict__ k_out,
                                                  unsigned* __restrict__ v_out) {
    __shared__ float at[128 * 68];     // normalized A_t[ci][pos], row stride 68
    __shared__ float wl[128 * 64];     // raw W[ci][half-local ch]
    int which = blockIdx.y;
    if (which == 0 && blockIdx.x >= 16) return;   // q: only 1024 rows
    int t = threadIdx.x;
    int half  = blockIdx.z;
    int n0 = blockIdx.x * 64;

    const float* W = (which == 0) ? Wq : (which == 1) ? Wk : Wv;
    const float* b = (which == 0) ? bq : (which == 1) ? bk : bv;
    {
        const float4* W4 = (const float4*)W;
        float4* wl4 = (float4*)wl;
        for (int i4 = t; i4 < 2048; i4 += 256) {
            int ci = i4 >> 4, j4 = i4 & 15;
            wl4[ci * 16 + j4] = W4[ci * 32 + half * 16 + j4];
        }
    }
    const float* mu = (which == 0) ? ws : ws + 2*DIM;
    const float* rs = (which == 0) ? ws + DIM : ws + 3*DIM;
    if (which == 0) {
        // x is (16,16,4) contiguous -> linear 1024 rows
        for (int i4 = t; i4 < 2048; i4 += 256) {
            int ci = i4 >> 4, ln4 = (i4 & 15) * 4;
            float4 f = *(const float4*)(x + ci * 1024 + n0 + ln4);
            float m_ = mu[ci], r_ = rs[ci];
            *(float4*)(at + ci * 68 + ln4) =
                make_float4((f.x - m_) * r_, (f.y - m_) * r_, (f.z - m_) * r_, (f.w - m_) * r_);
        }
    } else {
        for (int i4 = t; i4 < 2048; i4 += 256) {
            int ci = i4 >> 4, ln4 = (i4 & 15) * 4;
            float4 f = *(const float4*)(skip + (size_t)ci * NPOS + n0 + ln4);
            float m_ = mu[ci], r_ = rs[ci];
            *(float4*)(at + ci * 68 + ln4) =
                make_float4((f.x - m_) * r_, (f.y - m_) * r_, (f.z - m_) * r_, (f.w - m_) * r_);
        }
    }
    __syncthreads();

    int pg = t & 15, cg = t >> 4;
    float4 bv4 = *(const float4*)(b + half * 64 + cg * 4);
    float4 acc[4];
    #pragma unroll
    for (int ps = 0; ps < 4; ++ps) acc[ps] = bv4;

    const float* ap = at + pg * 4;
    const float* wp = wl + cg * 4;
    #pragma unroll 4
    for (int ci = 0; ci < 128; ++ci) {
        float4 a4 = *(const float4*)(ap + ci * 68);
        float4 w4 = *(const float4*)(wp + ci * 64);
        float av[4] = { a4.x, a4.y, a4.z, a4.w };
        #pragma unroll
        for (int ps = 0; ps < 4; ++ps) {
            float a = av[ps];
            acc[ps].x = fmaf(a, w4.x, acc[ps].x);
            acc[ps].y = fmaf(a, w4.y, acc[ps].y);
            acc[ps].z = fmaf(a, w4.z, acc[ps].z);
            acc[ps].w = fmaf(a, w4.w, acc[ps].w);
        }
    }
    int p0 = n0 + pg * 4;
    if (which == 0) {
        #pragma unroll
        for (int ps = 0; ps < 4; ++ps) {
            uint2 pk;
            pk.x = pkh(acc[ps].x * 0.25f, acc[ps].y * 0.25f);
            pk.y = pkh(acc[ps].z * 0.25f, acc[ps].w * 0.25f);
            *(uint2*)(q_out + (size_t)(p0 + ps) * 64 + half * 32 + cg * 2) = pk;
        }
    } else {
        unsigned* outp = (which == 1) ? k_out : v_out;
        #pragma unroll
        for (int ps = 0; ps < 4; ++ps) {
            uint2 pk;
            pk.x = pkh(acc[ps].x, acc[ps].y);
            pk.y = pkh(acc[ps].z, acc[ps].w);
            *(uint2*)(outp + (size_t)(p0 + ps) * 64 + half * 32 + cg * 2) = pk;
        }
    }
}

// ---------------- neighborhood attention: z-pair sharing ----------------
// Key fact: q rows for z-pair (2m,2m+1) are IDENTICAL (x upsampled 2x) and
// the pair shares h/w windows. One thread owns a z-pair: one QK dot and one
// k/v LDS read serve both positions -> LDS b128 traffic per (pos,nbr) halves.
// Pair iterates the union z-window (5x5x6 = 150 pts; ~17% masked when the two
// z-windows coincide). grid 512 = 64 tiles(4x4 h,w) x 8 heads; 512 thr =
// 64 z-pairs x 8 slots. Halo 8x8x8; LDS ~37 KB -> 2 blocks/CU, no grid tail.
__global__ __launch_bounds__(512, 4) void attn_kernel(const unsigned* __restrict__ qb,
                                                      const unsigned* __restrict__ kb,
                                                      const unsigned* __restrict__ vb,
                                                      const float* __restrict__ rpb,
                                                      float* __restrict__ ao_t) {
    __shared__ uint4 kbf[2 * 544];   // 17408 B, slot = gh*68 + gw*8 + ((gz+gw)&7)
    __shared__ uint4 vbf[2 * 544];   // 17408 B
    __shared__ float bias_l[744];    // 729 + zero pad (masked lanes may index 729..743)

    int blk = blockIdx.x;
    int h    = blk & 7;
    int tile = blk >> 3;             // 0..63
    int h0 = (tile >> 3) * 4;
    int w0 = (tile & 7) * 4;
    int bh0 = min(max(h0 - 2, 0), 24);
    int bw0 = min(max(w0 - 2, 0), 24);
    int t = threadIdx.x;

    // ---- stage k/v halo: 512 nbrs x 2 chunk-halves, direct 16B copies ----
    for (int idx = t; idx < 1024; idx += 512) {
        int c2 = idx & 1;
        int r  = idx >> 1;               // 0..511
        int gz = r & 7;
        int q2 = r >> 3;                 // 0..63
        int gh = q2 >> 3, gw = q2 & 7;
        int n = (bh0 + gh) * 256 + (bw0 + gw) * 8 + gz;
        int base = gh * 68 + gw * 8 + ((gz + gw) & 7);
        kbf[c2 * 544 + base] = *(const uint4*)(kb + (size_t)n * 64 + h * 8 + c2 * 4);
        vbf[c2 * 544 + base] = *(const uint4*)(vb + (size_t)n * 64 + h * 8 + c2 * 4);
    }
    for (int idx = t; idx < 744; idx += 512) bias_l[idx] = (idx < 729) ? rpb[h * 729 + idx] : 0.f;
    __syncthreads();

    int s = t & 7, p = t >> 3;           // 8 slots x 64 z-pairs
    int ph = p >> 4, pw = (p >> 2) & 3, pzp = p & 3;
    int hc = h0 + ph, wc = w0 + pw, zc0 = pzp * 2;   // pair = (zc0, zc0+1)
    int sh = min(max(hc - 2, 0), 27);
    int sw = min(max(wc - 2, 0), 27);
    int sz0 = min(max(zc0 - 2, 0), 3);
    int sz1 = min(max(zc0 - 1, 0), 3);
    int dlt = sz1 - sz0;                 // 0 or 1: z-window shift of pos1 vs pos0
    int hb = sh - bh0, wb = sw - bw0;
    int b0 = (sh - hc + 4) * 81 + (sw - wc + 4) * 9 + (sz0 - zc0 + 4);
    // bias index for pos1 = b0 - 1 (zc1 = zc0+1, same zlo)
    int n0pos = hc * 256 + wc * 8 + zc0;

    // shared q (identical for both z's of the pair), f16-packed: 8 ch-pairs
    int qrow = (hc >> 1) * 64 + (wc >> 1) * 4 + pzp;
    uint4 qa = *(const uint4*)(qb + (size_t)qrow * 64 + h * 8);
    uint4 qc = *(const uint4*)(qb + (size_t)qrow * 64 + h * 8 + 4);

    float o0[16], o1[16];
    #pragma unroll
    for (int d = 0; d < 16; ++d) { o0[d] = 0.f; o1[d] = 0.f; }
    float l0 = 0.f, l1 = 0.f;

    // slot partition of the 150 union points: s<6 -> 19, else 18
    int cnt   = 18 + (s < 6);
    int start = s * 18 + min(s, 6);
    int i0 = p & 15;                     // stagger (15 < 18 always)

    for (int it = 0; it < cnt; ++it) {
        int ii = i0 + it; if (ii >= cnt) ii -= cnt;
        int j = start + ii;              // 0..149
        int jh = (j * 2185) >> 16;       // j / 30
        int jr = j - jh * 30;
        int jw = (jr * 43) >> 8;         // jr / 6
        int jz = jr - jw * 6;            // 0..5 (union z index)
        int gw = wb + jw;
        int gz = sz0 + jz;
        int base = (hb + jh) * 68 + gw * 8 + ((gz + gw) & 7);
        int joff = jh * 81 + jw * 9 + jz;
        float bias1 = bias_l[b0 + joff - 1];
        float bias0 = bias_l[b0 + joff];

        uint4 ka = kbf[base];
        uint4 k2 = kbf[544 + base];
        float d0 = dot2(ka.x, qa.x, 0.f);
        float d1 = dot2(ka.y, qa.y, 0.f);
        d0 = dot2(ka.z, qa.z, d0);
        d1 = dot2(ka.w, qa.w, d1);
        d0 = dot2(k2.x, qc.x, d0);
        d1 = dot2(k2.y, qc.y, d1);
        d0 = dot2(k2.z, qc.z, d0);
        d1 = dot2(k2.w, qc.w, d1);
        float d = d0 + d1;               // shared: q identical for the pair

        bool v0ok = (jz < 5);                         // pos0 window: [0,4]
        bool v1ok = ((unsigned)(jz - dlt) < 5u);      // pos1 window: [dlt, dlt+4]
        float e0 = __expf(d + bias0);
        float e1 = __expf(d + bias1);
        float pp0 = v0ok ? e0 : 0.f;
        float pp1 = v1ok ? e1 : 0.f;
        l0 += pp0; l1 += pp1;

        uint4 va = vbf[base];
        uint4 v2 = vbf[544 + base];
        #define PV(u, dd) { half2_t vh = u2h(u); float f0 = (float)vh.x, f1 = (float)vh.y; \
            o0[dd]   = fmaf(pp0, f0, o0[dd]);   o1[dd]   = fmaf(pp1, f0, o1[dd]); \
            o0[dd+1] = fmaf(pp0, f1, o0[dd+1]); o1[dd+1] = fmaf(pp1, f1, o1[dd+1]); }
        PV(va.x, 0)  PV(va.y, 2)  PV(va.z, 4)  PV(va.w, 6)
        PV(v2.x, 8)  PV(v2.y, 10) PV(v2.z, 12) PV(v2.w, 14)
        #undef PV
    }

    // merge 8 slots (adjacent lanes)
    #pragma unroll
    for (int step = 1; step <= 4; step <<= 1) {
        l0 += __shfl_xor(l0, step, 64);
        l1 += __shfl_xor(l1, step, 64);
        #pragma unroll
        for (int d = 0; d < 16; ++d) {
            o0[d] += __shfl_xor(o0[d], step, 64);
            o1[d] += __shfl_xor(o1[d], step, 64);
        }
    }
    float inv0 = 1.f / l0, inv1 = 1.f / l1;
    // lane s stores dims 2s, 2s+1 for both positions (cols n0pos, n0pos+1)
    int row = h * 16 + 2 * s;
    float2 r0 = make_float2(o0[2*s]     * inv0, o1[2*s]     * inv1);
    float2 r1 = make_float2(o0[2*s + 1] * inv0, o1[2*s + 1] * inv1);
    *(float2*)(ao_t + (size_t)row       * NPOS + n0pos) = r0;
    *(float2*)(ao_t + (size_t)(row + 1) * NPOS + n0pos) = r1;
}

// ---------------- output projection: 4pos x 4ch, A (ao_t) transposed in LDS ----------------
__global__ __launch_bounds__(256) void proj_kernel(const float* __restrict__ ao_t,
                                                   const float* __restrict__ Wo,
                                                   const float* __restrict__ bo,
                                                   float* __restrict__ out) {
    __shared__ float at[128 * 68];
    __shared__ float wl[128 * 64];
    int t = threadIdx.x;
    int half = blockIdx.y;
    int n0 = blockIdx.x * 64;

    {
        const float4* W4 = (const float4*)Wo;
        float4* wl4 = (float4*)wl;
        for (int i4 = t; i4 < 2048; i4 += 256) {
            int ci = i4 >> 4, j4 = i4 & 15;
            wl4[ci * 16 + j4] = W4[ci * 32 + half * 16 + j4];
        }
    }
    for (int i4 = t; i4 < 2048; i4 += 256) {
        int ci = i4 >> 4, ln4 = (i4 & 15) * 4;
        float4 f = *(const float4*)(ao_t + (size_t)ci * NPOS + n0 + ln4);
        *(float4*)(at + ci * 68 + ln4) = f;
    }
    __syncthreads();

    int pg = t & 15, cg = t >> 4;
    float4 bv4 = *(const float4*)(bo + half * 64 + cg * 4);
    float4 acc[4];
    #pragma unroll
    for (int ps = 0; ps < 4; ++ps) acc[ps] = bv4;

    const float* ap = at + pg * 4;
    const float* wp = wl + cg * 4;
    #pragma unroll 4
    for (int ci = 0; ci < 128; ++ci) {
        float4 a4 = *(const float4*)(ap + ci * 68);
        float4 w4 = *(const float4*)(wp + ci * 64);
        float av[4] = { a4.x, a4.y, a4.z, a4.w };
        #pragma unroll
        for (int ps = 0; ps < 4; ++ps) {
            float a = av[ps];
            acc[ps].x = fmaf(a, w4.x, acc[ps].x);
            acc[ps].y = fmaf(a, w4.y, acc[ps].y);
            acc[ps].z = fmaf(a, w4.z, acc[ps].z);
            acc[ps].w = fmaf(a, w4.w, acc[ps].w);
        }
    }
    int p0 = n0 + pg * 4;
    int jbase = half * 64 + cg * 4;
    *(float4*)(out + (size_t)(jbase + 0) * NPOS + p0) = make_float4(acc[0].x, acc[1].x, acc[2].x, acc[3].x);
    *(float4*)(out + (size_t)(jbase + 1) * NPOS + p0) = make_float4(acc[0].y, acc[1].y, acc[2].y, acc[3].y);
    *(float4*)(out + (size_t)(jbase + 2) * NPOS + p0) = make_float4(acc[0].z, acc[1].z, acc[2].z, acc[3].z);
    *(float4*)(out + (size_t)(jbase + 3) * NPOS + p0) = make_float4(acc[0].w, acc[1].w, acc[2].w, acc[3].w);
}

extern "C" void kernel_launch(void* const* d_in, const int* in_sizes, int n_in,
                              void* d_out, int out_size, void* d_ws, size_t ws_size,
                              hipStream_t stream) {
    const float* x    = (const float*)d_in[0];
    const float* skip = (const float*)d_in[1];
    const float* Wq   = (const float*)d_in[2];
    const float* bq   = (const float*)d_in[3];
    const float* Wk   = (const float*)d_in[4];
    const float* bk   = (const float*)d_in[5];
    const float* Wv   = (const float*)d_in[6];
    const float* bv   = (const float*)d_in[7];
    const float* rpb  = (const float*)d_in[8];
    const float* Wo   = (const float*)d_in[9];
    const float* bo   = (const float*)d_in[10];
    float* out = (float*)d_out;

    float*    ws   = (float*)d_ws;
    unsigned* q    = (unsigned*)(ws + 512);              // 1024*64 uints (f16x2), 256 KB
    unsigned* kbp  = q + 1024 * 64;                      // 8192*64 uints packed f16
    unsigned* vbp  = kbp + (size_t)NPOS * 64;
    float*    ao_t = (float*)(vbp + (size_t)NPOS * 64);  // 8192*128 fp32

    stats_kernel<<<256, 256, 0, stream>>>(x, skip, ws);
    qkv_kernel<<<dim3(128, 3, 2), 256, 0, stream>>>(x, skip, Wq, bq, Wk, bk, Wv, bv, ws, q, kbp, vbp);
    attn_kernel<<<512, 512, 0, stream>>>(q, kbp, vbp, rpb, ao_t);
    proj_kernel<<<dim3(128, 2), 256, 0, stream>>>(ao_t, Wo, bo, out);
}